// Round 10
// baseline (477.185 us; speedup 1.0000x reference)
//
#include <hip/hip_runtime.h>

// 8-level sym8 wavelet packet transform, B=128 rows of L0=65536, f32.
// 3 fused kernels: F01 (levels 0-1), F23 (levels 2-3), F47 (levels 4-7).
// Lengths: 65536->32775->16395->8205->4110->2062->1038->526->270.
// R6 geometry (NO=2 interleaved, dense 4u window base = conflict-minimal,
// virtual A-tile in pair kernels, 14-float mirrored margins in quad), plus
// R9 change: every hot loop processes TWO groups per iteration with both
// groups' 5x ds_read_b128 issued before either convolution -> ~10 reads in
// flight, counted lgkmcnt waits, 2x register pressure (still <=64 VGPR).

#define BT 512

// fl[t] = dec_lo[15-t]  (flipped low-pass, cross-correlation form)
__device__ __constant__ float FL[16] = {
     0.0018899503327594609f, -0.0003029205147213668f, -0.01495225833704823f,
     0.003808752013890615f,   0.049137179673607506f,  -0.027219029917056003f,
    -0.05194583810770904f,    0.3644418948353314f,     0.7771857517005235f,
     0.4813596512583722f,    -0.061273359067658524f,  -0.1432942383508097f,
     0.007607487324917605f,   0.03169508781149298f,   -0.0005421323317911481f,
    -0.0033824159510061256f
};

// fh[t] = dec_hi[15-t] = (t odd ? +1 : -1) * dec_lo[t]
__device__ __constant__ float FH[16] = {
     0.0033824159510061256f, -0.0005421323317911481f, -0.03169508781149298f,
     0.007607487324917605f,   0.1432942383508097f,    -0.061273359067658524f,
    -0.4813596512583722f,     0.7771857517005235f,    -0.3644418948353314f,
    -0.05194583810770904f,    0.027219029917056003f,   0.049137179673607506f,
    -0.003808752013890615f,  -0.01495225833704823f,    0.0003029205147213668f,
     0.0018899503327594609f
};

__device__ __forceinline__ int reflect(int q, int L) {
    q = (q < 0) ? -q : q;
    return (q >= L) ? (2 * L - 2 - q) : q;
}

// Mirror write into an ext buffer. ext = EXT BASE (genuine j lives at ext[14+j]).
__device__ __forceinline__ void mirror_put(float* ext, int LOUTc, int j, float v) {
    if (j >= 1 && j <= 14) ext[14 - j] = v;
    if (j >= LOUTc - 15 && j <= LOUTc - 2) ext[2 * LOUTc + 12 - j] = v;
}

// Load 20-float window from LDS: 5 x ds_read_b128 (base must be mult of 4).
__device__ __forceinline__ void load20(const float* __restrict__ lds, int base,
                                       float w[20]) {
#pragma unroll
    for (int k = 0; k < 5; ++k) {
        const float4 v = *reinterpret_cast<const float4*>(&lds[base + 4 * k]);
        w[4 * k] = v.x; w[4 * k + 1] = v.y; w[4 * k + 2] = v.z; w[4 * k + 3] = v.w;
    }
}

// Convolve positions (j, j+1) with both filters from an 18-tap window.
__device__ __forceinline__ void conv2(const float w[20], float& lo0, float& hi0,
                                      float& lo1, float& hi1) {
    lo0 = hi0 = lo1 = hi1 = 0.f;
#pragma unroll
    for (int t = 0; t < 16; ++t) {
        const float cl = FL[t], ch = FH[t];
        lo0 = fmaf(w[t], cl, lo0);
        hi0 = fmaf(w[t], ch, hi0);
        lo1 = fmaf(w[t + 2], cl, lo1);
        hi1 = fmaf(w[t + 2], ch, hi1);
    }
}

// A-phase edge group: positions a, a+1 via reflect in A-index space.
__device__ __forceinline__ void a_edge_group(const float* __restrict__ xs, int a,
                                             int LA, int a_lo,
                                             float& lo0, float& hi0,
                                             float& lo1, float& hi1) {
#pragma unroll
    for (int e = 0; e < 2; ++e) {
        const int ga = reflect(a + e, LA);
        const int bb = 2 * (ga - a_lo);
        float l = 0.f, h = 0.f;
#pragma unroll
        for (int t = 0; t < 16; ++t) {
            const float v = xs[bb + t];
            l = fmaf(v, FL[t], l);
            h = fmaf(v, FH[t], h);
        }
        if (e == 0) { lo0 = l; hi0 = h; } else { lo1 = l; hi1 = h; }
    }
}

// ---------------- Fused two-level kernel (levels k, k+1) ----------------
template <int LIN, int LA, int LB, int SIN, int SOUT, int MB>
__global__ __launch_bounds__(BT, 8) void dwt_pair2(
    const float* __restrict__ x, float* __restrict__ y) {
    constexpr int WA  = 2 * MB + 14;            // virtual A-tile width (even)
    constexpr int WAp = (WA + 2 + 3) & ~3;      // subband stride (mult 4)
    constexpr int WX  = 2 * WA + 14;
    constexpr int XSp = (WX + 2 + 3) & ~3;
    constexpr int PP  = WA / 2;                 // A-phase pairs
    constexpr int GH  = MB / 2;                 // B-phase pairs per subband
    __shared__ __align__(16) float xs[XSp];
    __shared__ __align__(16) float as[2 * WAp];

    const int seg  = blockIdx.x;
    const int n    = blockIdx.y;
    const int b0   = seg * MB;
    const int a_lo = 2 * b0 - 14;
    const int px0  = 2 * a_lo - 14;             // even
    const float* row = x + (size_t)n * (size_t)SIN;

    // ---- x-tile fill (paired loads) ----
    if (px0 >= 0 && px0 + WX <= LIN) {
        const float2* rp = reinterpret_cast<const float2*>(row + px0);
        constexpr int HN = WX / 2;
        for (int h = threadIdx.x; h < HN; h += 2 * BT) {
            const int h1 = h + BT;
            const bool has = h1 < HN;
            const float2 v0 = rp[h];
            float2 v1;
            if (has) v1 = rp[h1];
            *reinterpret_cast<float2*>(&xs[2 * h]) = v0;
            if (has) *reinterpret_cast<float2*>(&xs[2 * h1]) = v1;
        }
    } else {
        for (int p = threadIdx.x; p < WX; p += BT)
            xs[p] = row[reflect(px0 + p, LIN)];
    }
    __syncthreads();

    // ---- A-phase (paired groups) ----
    const int jbmax = ((b0 + MB < LB) ? (b0 + MB) : LB) - 1;
    const int smax  = 2 * (jbmax - b0) + 15;
    const int PPlim = (smax >> 1) + 1;
    const int PPeff = (PPlim < PP) ? PPlim : PP;
    for (int g = threadIdx.x; g < PPeff; g += 2 * BT) {
        const int g1  = g + BT;
        const bool has = g1 < PPeff;
        const int aA = a_lo + 2 * g;
        const int aB = a_lo + 2 * g1;
        const bool iA = (aA >= 0) && (aA + 1 < LA);
        const bool iB = (aB >= 0) && (aB + 1 < LA);
        float lo0A, hi0A, lo1A, hi1A;
        float lo0B, hi0B, lo1B, hi1B;
        if (iA && (!has || iB)) {               // fast path: both interior
            float wA[20], wB[20];
            load20(xs, 4 * g, wA);
            if (has) load20(xs, 4 * g1, wB);
            conv2(wA, lo0A, hi0A, lo1A, hi1A);
            if (has) conv2(wB, lo0B, hi0B, lo1B, hi1B);
        } else {                                // rare: tile edges
            if (iA) {
                float wA[20];
                load20(xs, 4 * g, wA);
                conv2(wA, lo0A, hi0A, lo1A, hi1A);
            } else {
                a_edge_group(xs, aA, LA, a_lo, lo0A, hi0A, lo1A, hi1A);
            }
            if (has) {
                if (iB) {
                    float wB[20];
                    load20(xs, 4 * g1, wB);
                    conv2(wB, lo0B, hi0B, lo1B, hi1B);
                } else {
                    a_edge_group(xs, aB, LA, a_lo, lo0B, hi0B, lo1B, hi1B);
                }
            }
        }
        *reinterpret_cast<float2*>(&as[2 * g])        = make_float2(lo0A, lo1A);
        *reinterpret_cast<float2*>(&as[WAp + 2 * g])  = make_float2(hi0A, hi1A);
        if (has) {
            *reinterpret_cast<float2*>(&as[2 * g1])       = make_float2(lo0B, lo1B);
            *reinterpret_cast<float2*>(&as[WAp + 2 * g1]) = make_float2(hi0B, hi1B);
        }
    }
    __syncthreads();

    // ---- B-phase (paired groups) ----
    for (int g = threadIdx.x; g < 2 * GH; g += 2 * BT) {
        const int g1 = g + BT;
        const bool has = g1 < 2 * GH;
        const int sA0 = (g >= GH) ? 1 : 0;
        const int u0  = g - sA0 * GH;
        const int j0  = b0 + 2 * u0;
        const bool ok0 = j0 < LB;
        int sA1 = 0, u1 = 0, j1 = 0;
        bool ok1 = false;
        if (has) {
            sA1 = (g1 >= GH) ? 1 : 0;
            u1  = g1 - sA1 * GH;
            j1  = b0 + 2 * u1;
            ok1 = j1 < LB;
        }
        float wA[20], wB[20];
        if (ok0) load20(as, sA0 * WAp + 4 * u0, wA);
        if (ok1) load20(as, sA1 * WAp + 4 * u1, wB);
        if (ok0) {
            float lo0, hi0, lo1, hi1;
            conv2(wA, lo0, hi0, lo1, hi1);
            float* y0 = y + (size_t)(4 * n + 2 * sA0) * (size_t)SOUT + (size_t)j0;
            float* y1 = y0 + SOUT;
            if (j0 + 1 < LB) {
                *reinterpret_cast<float2*>(y0) = make_float2(lo0, lo1);
                *reinterpret_cast<float2*>(y1) = make_float2(hi0, hi1);
            } else {
                y0[0] = lo0; y1[0] = hi0;
            }
        }
        if (ok1) {
            float lo0, hi0, lo1, hi1;
            conv2(wB, lo0, hi0, lo1, hi1);
            float* y0 = y + (size_t)(4 * n + 2 * sA1) * (size_t)SOUT + (size_t)j1;
            float* y1 = y0 + SOUT;
            if (j1 + 1 < LB) {
                *reinterpret_cast<float2*>(y0) = make_float2(lo0, lo1);
                *reinterpret_cast<float2*>(y1) = make_float2(hi0, hi1);
            } else {
                y0[0] = lo0; y1[0] = hi0;
            }
        }
    }
}

// ---------------- Fused four-level kernel (levels 4-7) ----------------
// ext layout per subrow: [14 reflected | L genuine | 14 reflected | pad].
template <int LOUT, int Sout, bool LOG>
__device__ __forceinline__ void stage_emit(const float w[20], int p, int u,
                                           float* __restrict__ outb,
                                           float* __restrict__ outg) {
    float lo0, hi0, lo1, hi1;
    conv2(w, lo0, hi0, lo1, hi1);
    const int j0 = 2 * u;
    if (LOG) {
        float* o0 = outg + (size_t)(2 * p) * 270 + j0;
        float* o1 = o0 + 270;
        *reinterpret_cast<float2*>(o0) =
            make_float2(__logf(fmaf(lo0, lo0, 1e-12f)),
                        __logf(fmaf(lo1, lo1, 1e-12f)));
        *reinterpret_cast<float2*>(o1) =
            make_float2(__logf(fmaf(hi0, hi0, 1e-12f)),
                        __logf(fmaf(hi1, hi1, 1e-12f)));
    } else {
        float* e0 = outb + (2 * p) * Sout;      // EXT BASE pointers
        float* e1 = e0 + Sout;
        *reinterpret_cast<float2*>(e0 + 14 + j0) = make_float2(lo0, lo1);
        *reinterpret_cast<float2*>(e1 + 14 + j0) = make_float2(hi0, hi1);
        if (j0 <= 14 || j0 >= LOUT - 16) {
            mirror_put(e0, LOUT, j0, lo0);
            mirror_put(e0, LOUT, j0 + 1, lo1);
            mirror_put(e1, LOUT, j0, hi0);
            mirror_put(e1, LOUT, j0 + 1, hi1);
        }
    }
}

template <int L, int P, int Sin, int Sout, bool LOG>
__device__ __forceinline__ void stage2x(const float* __restrict__ inb,
                                        float* __restrict__ outb,
                                        float* __restrict__ outg) {
    constexpr int LOUT = L / 2 + 7;             // even for all our stages
    constexpr int PP   = LOUT / 2;
    constexpr int G    = P * PP;
    for (int g = threadIdx.x; g < G; g += 2 * BT) {
        const int g1 = g + BT;
        const bool has = g1 < G;
        int p0, u0, p1 = 0, u1 = 0;
        if constexpr (P == 1) {
            p0 = 0; u0 = g;
            if (has) { p1 = 0; u1 = g1; }
        } else {
            p0 = g / PP; u0 = g - p0 * PP;
            if (has) { p1 = g1 / PP; u1 = g1 - p1 * PP; }
        }
        float wA[20], wB[20];
        load20(inb, p0 * Sin + 4 * u0, wA);
        if (has) load20(inb, p1 * Sin + 4 * u1, wB);
        stage_emit<LOUT, Sout, LOG>(wA, p0, u0, outb, outg);
        if (has) stage_emit<LOUT, Sout, LOG>(wB, p1, u1, outb, outg);
    }
}

__global__ __launch_bounds__(BT, 8) void dwt_quad2(
    const float* __restrict__ x, float* __restrict__ y) {
    // ext strides (mult of 4, cover b128 over-read)
    constexpr int S1 = 4140, S2 = 2092, S3 = 1068, S4 = 556;
    __shared__ __align__(16) float bufA[4272];  // input ext (4140) | s2 out 4x1068
    __shared__ __align__(16) float bufB[4448];  // s1 out 2x2092 | s3 out 8x556

    const int m = blockIdx.x;
    const float* row = x + (size_t)m * 4112;
    const float2* rp = reinterpret_cast<const float2*>(row);

    // fill input ext (paired): bufA[14+p] = row[p], p in [0,4110)
    for (int h = threadIdx.x; h < 2055; h += 2 * BT) {
        const int h1 = h + BT;
        const bool has = h1 < 2055;
        const float2 v0 = rp[h];
        float2 v1;
        if (has) v1 = rp[h1];
        {
            const int p = 2 * h;
            *reinterpret_cast<float2*>(&bufA[14 + p]) = v0;
            if (p <= 14 || p >= 4110 - 16) {
                mirror_put(bufA, 4110, p, v0.x);
                mirror_put(bufA, 4110, p + 1, v0.y);
            }
        }
        if (has) {
            const int p = 2 * h1;
            *reinterpret_cast<float2*>(&bufA[14 + p]) = v1;
            if (p <= 14 || p >= 4110 - 16) {
                mirror_put(bufA, 4110, p, v1.x);
                mirror_put(bufA, 4110, p + 1, v1.y);
            }
        }
    }
    __syncthreads();

    stage2x<4110, 1, S1, S2, false>(bufA, bufB, nullptr);  // -> 2 x 2062
    __syncthreads();
    stage2x<2062, 2, S2, S3, false>(bufB, bufA, nullptr);  // -> 4 x 1038
    __syncthreads();
    stage2x<1038, 4, S3, S4, false>(bufA, bufB, nullptr);  // -> 8 x 526
    __syncthreads();
    stage2x<526, 8, S4, 0, true>(bufB, nullptr, y + (size_t)m * 4320);  // 16 x 270
}

extern "C" void kernel_launch(void* const* d_in, const int* in_sizes, int n_in,
                              void* d_out, int out_size, void* d_ws, size_t ws_size,
                              hipStream_t stream) {
    const float* in = (const float*)d_in[0];
    float* out = (float*)d_out;
    float* wsA = (float*)d_ws;              // lev1: 512 rows, stride 16396
    float* wsB = (float*)d_ws + 8400000;    // lev3: 2048 rows, stride 4112
    (void)ws_size; (void)out_size; (void)n_in; (void)in_sizes;

    // F01: 65536 -> 32775 -> 16395; MB=1026, 16 segs
    { dim3 g(16, 128); dwt_pair2<65536, 32775, 16395, 65536, 16396, 1026>
          <<<g, BT, 0, stream>>>(in, wsA); }
    // F23: 16395 -> 8205 -> 4110; MB=1028, 4 segs
    { dim3 g(4, 512);  dwt_pair2<16395, 8205, 4110, 16396, 4112, 1028>
          <<<g, BT, 0, stream>>>(wsA, wsB); }
    // F47: 4110 -> 2062 -> 1038 -> 526 -> 270(+log)
    dwt_quad2<<<2048, BT, 0, stream>>>(wsB, out);
}

// Round 11
// 101.310 us; speedup vs baseline: 4.7102x; 4.7102x over previous
//
#include <hip/hip_runtime.h>

// 8-level sym8 wavelet packet transform, B=128 rows of L0=65536, f32.
// 3 fused kernels: F01 (levels 0-1), F23 (levels 2-3), F47 (levels 4-7).
// Lengths: 65536->32775->16395->8205->4110->2062->1038->526->270.
// R6 geometry (NO=2 interleaved, dense 4u window base, virtual A-tile in
// pair kernels, 14-float mirrored margins in quad). R10: 2-group software
// pipelining in quad stages + pair B-phase, SCRATCH-FREE form: clamped
// indices (gB = min(g+BT, G-1)), unconditional straight-line loads/convs,
// only register stores guarded. Duplicate clamped writes are same-value
// same-address (benign).

#define BT 512

// fl[t] = dec_lo[15-t]  (flipped low-pass, cross-correlation form)
__device__ __constant__ float FL[16] = {
     0.0018899503327594609f, -0.0003029205147213668f, -0.01495225833704823f,
     0.003808752013890615f,   0.049137179673607506f,  -0.027219029917056003f,
    -0.05194583810770904f,    0.3644418948353314f,     0.7771857517005235f,
     0.4813596512583722f,    -0.061273359067658524f,  -0.1432942383508097f,
     0.007607487324917605f,   0.03169508781149298f,   -0.0005421323317911481f,
    -0.0033824159510061256f
};

// fh[t] = dec_hi[15-t] = (t odd ? +1 : -1) * dec_lo[t]
__device__ __constant__ float FH[16] = {
     0.0033824159510061256f, -0.0005421323317911481f, -0.03169508781149298f,
     0.007607487324917605f,   0.1432942383508097f,    -0.061273359067658524f,
    -0.4813596512583722f,     0.7771857517005235f,    -0.3644418948353314f,
    -0.05194583810770904f,    0.027219029917056003f,   0.049137179673607506f,
    -0.003808752013890615f,  -0.01495225833704823f,    0.0003029205147213668f,
     0.0018899503327594609f
};

__device__ __forceinline__ int reflect(int q, int L) {
    q = (q < 0) ? -q : q;
    return (q >= L) ? (2 * L - 2 - q) : q;
}

// Mirror write into an ext buffer. ext = EXT BASE (genuine j lives at ext[14+j]).
__device__ __forceinline__ void mirror_put(float* ext, int LOUTc, int j, float v) {
    if (j >= 1 && j <= 14) ext[14 - j] = v;
    if (j >= LOUTc - 15 && j <= LOUTc - 2) ext[2 * LOUTc + 12 - j] = v;
}

// Load 20-float window from LDS: 5 x ds_read_b128 (base must be mult of 4).
__device__ __forceinline__ void load20(const float* __restrict__ lds, int base,
                                       float w[20]) {
#pragma unroll
    for (int k = 0; k < 5; ++k) {
        const float4 v = *reinterpret_cast<const float4*>(&lds[base + 4 * k]);
        w[4 * k] = v.x; w[4 * k + 1] = v.y; w[4 * k + 2] = v.z; w[4 * k + 3] = v.w;
    }
}

// Convolve positions (j, j+1) with both filters from an 18-tap window.
__device__ __forceinline__ void conv2(const float w[20], float& lo0, float& hi0,
                                      float& lo1, float& hi1) {
    lo0 = hi0 = lo1 = hi1 = 0.f;
#pragma unroll
    for (int t = 0; t < 16; ++t) {
        const float cl = FL[t], ch = FH[t];
        lo0 = fmaf(w[t], cl, lo0);
        hi0 = fmaf(w[t], ch, hi0);
        lo1 = fmaf(w[t + 2], cl, lo1);
        hi1 = fmaf(w[t + 2], ch, hi1);
    }
}

// ---------------- Fused two-level kernel (levels k, k+1) ----------------
template <int LIN, int LA, int LB, int SIN, int SOUT, int MB>
__global__ __launch_bounds__(BT, 8) void dwt_pair(
    const float* __restrict__ x, float* __restrict__ y) {
    constexpr int WA  = 2 * MB + 14;                 // virtual A-tile width (even)
    constexpr int WAp = (WA + 2 + 3) & ~3;           // subband stride (mult 4, +pad)
    constexpr int WX  = 2 * WA + 14;                 // x-tile width (even)
    constexpr int WXp = (WX + 2 + 3) & ~3;           // with b128 over-read pad
    constexpr int PP  = WA / 2;                      // A-phase pairs
    constexpr int GH  = MB / 2;                      // B-phase pairs per subband
    __shared__ __align__(16) float xs[WXp];
    __shared__ __align__(16) float as[2 * WAp];

    const int seg = blockIdx.x;
    const int n   = blockIdx.y;
    const int b0  = seg * MB;
    const int a_lo = 2 * b0 - 14;        // virtual tile start (may be <0 / >LA-WA)
    const int px0  = 2 * a_lo - 14;      // x coordinate of xs[0] (always even)

    const float* row = x + (size_t)n * (size_t)SIN;

    // ---- x-tile fill ----
    if (px0 >= 0 && px0 + WX <= LIN) {
        const float2* rp = reinterpret_cast<const float2*>(row + px0);
        for (int h = threadIdx.x; h < WX / 2; h += BT) {
            *reinterpret_cast<float2*>(&xs[2 * h]) = rp[h];
        }
    } else {
        for (int p = threadIdx.x; p < WX; p += BT) {
            xs[p] = row[reflect(px0 + p, LIN)];
        }
    }
    __syncthreads();

    // ---- A-phase: virtual positions a_lo+s, s in [0, WA) (R6 verbatim) ----
    const int jbmax = ((b0 + MB < LB) ? (b0 + MB) : LB) - 1;
    const int smax  = 2 * (jbmax - b0) + 15;    // max tile-s read by B
    for (int g = threadIdx.x; g < PP; g += BT) {
        const int s0 = 2 * g;
        if (s0 > smax) continue;
        const int a  = a_lo + s0;
        float lo0, hi0, lo1, hi1;
        if (a >= 0 && a + 1 < LA) {
            float w[20];
            load20(xs, 4 * g, w);        // rel window = [2*s0, 2*s0+17]
            conv2(w, lo0, hi0, lo1, hi1);
        } else {
#pragma unroll
            for (int e = 0; e < 2; ++e) {
                const int ga = reflect(a + e, LA);
                const int bb = 2 * ga - 14 - px0;    // even, in-range
                float l = 0.f, h = 0.f;
#pragma unroll
                for (int t = 0; t < 16; ++t) {
                    const float v = xs[bb + t];
                    l = fmaf(v, FL[t], l);
                    h = fmaf(v, FH[t], h);
                }
                if (e == 0) { lo0 = l; hi0 = h; } else { lo1 = l; hi1 = h; }
            }
        }
        *reinterpret_cast<float2*>(&as[s0])       = make_float2(lo0, lo1);
        *reinterpret_cast<float2*>(&as[WAp + s0]) = make_float2(hi0, hi1);
    }
    __syncthreads();

    // ---- B-phase: paired groups (g, min(g+BT, G-1)), scratch-free ----
    constexpr int GBB = 2 * GH;
    for (int g = threadIdx.x; g < GBB; g += 2 * BT) {
        const int gB  = (g + BT < GBB) ? (g + BT) : (GBB - 1);
        const int sA0 = (g >= GH) ? 1 : 0;
        const int u0  = g - sA0 * GH;
        const int ja  = b0 + 2 * u0;
        const int sA1 = (gB >= GH) ? 1 : 0;
        const int u1  = gB - sA1 * GH;
        const int jb  = b0 + 2 * u1;

        float wA[20], wB[20];
        load20(as, sA0 * WAp + 4 * u0, wA);      // both loads in flight
        load20(as, sA1 * WAp + 4 * u1, wB);
        float la0, ha0, la1, ha1, lb0, hb0, lb1, hb1;
        conv2(wA, la0, ha0, la1, ha1);
        conv2(wB, lb0, hb0, lb1, hb1);

        if (ja < LB) {
            float* y0 = y + (size_t)(4 * n + 2 * sA0) * (size_t)SOUT + (size_t)ja;
            float* y1 = y0 + SOUT;
            if (ja + 1 < LB) {
                *reinterpret_cast<float2*>(y0) = make_float2(la0, la1);
                *reinterpret_cast<float2*>(y1) = make_float2(ha0, ha1);
            } else {
                y0[0] = la0; y1[0] = ha0;
            }
        }
        if (jb < LB) {
            float* y0 = y + (size_t)(4 * n + 2 * sA1) * (size_t)SOUT + (size_t)jb;
            float* y1 = y0 + SOUT;
            if (jb + 1 < LB) {
                *reinterpret_cast<float2*>(y0) = make_float2(lb0, lb1);
                *reinterpret_cast<float2*>(y1) = make_float2(hb0, hb1);
            } else {
                y0[0] = lb0; y1[0] = hb0;
            }
        }
    }
}

// ---------------- Fused four-level kernel (levels 4-7) ----------------
// ext layout per subrow: [14 reflected | L genuine | 14 reflected | pad]
template <int LOUT, int Sout, bool LOG>
__device__ __forceinline__ void emit(const float w[20], int p, int u,
                                     float* __restrict__ outb,
                                     float* __restrict__ outg) {
    float lo0, hi0, lo1, hi1;
    conv2(w, lo0, hi0, lo1, hi1);
    const int j0 = 2 * u;
    if (LOG) {
        float* o0 = outg + (size_t)(2 * p) * 270 + j0;
        float* o1 = o0 + 270;
        *reinterpret_cast<float2*>(o0) =
            make_float2(__logf(fmaf(lo0, lo0, 1e-12f)),
                        __logf(fmaf(lo1, lo1, 1e-12f)));
        *reinterpret_cast<float2*>(o1) =
            make_float2(__logf(fmaf(hi0, hi0, 1e-12f)),
                        __logf(fmaf(hi1, hi1, 1e-12f)));
    } else {
        float* e0 = outb + (2 * p) * Sout;       // EXT BASE pointers
        float* e1 = e0 + Sout;
        *reinterpret_cast<float2*>(e0 + 14 + j0) = make_float2(lo0, lo1);
        *reinterpret_cast<float2*>(e1 + 14 + j0) = make_float2(hi0, hi1);
        if (j0 <= 14 || j0 >= LOUT - 16) {
            mirror_put(e0, LOUT, j0, lo0);
            mirror_put(e0, LOUT, j0 + 1, lo1);
            mirror_put(e1, LOUT, j0, hi0);
            mirror_put(e1, LOUT, j0 + 1, hi1);
        }
    }
}

template <int L, int P, int Sin, int Sout, bool LOG>
__device__ __forceinline__ void stage(const float* __restrict__ inb,
                                      float* __restrict__ outb,
                                      float* __restrict__ outg) {
    constexpr int LOUT = L / 2 + 7;              // even for all our stages
    constexpr int PP   = LOUT / 2;
    constexpr int G    = P * PP;
    for (int g = threadIdx.x; g < G; g += 2 * BT) {
        const int gB = (g + BT < G) ? (g + BT) : (G - 1);
        int pA, uA, pB, uB;
        if constexpr (P == 1) {
            pA = 0; uA = g; pB = 0; uB = gB;
        } else {
            pA = g / PP;  uA = g - pA * PP;      // compile-time divisor
            pB = gB / PP; uB = gB - pB * PP;
        }
        float wA[20], wB[20];
        load20(inb, pA * Sin + 4 * uA, wA);      // both loads in flight
        load20(inb, pB * Sin + 4 * uB, wB);
        emit<LOUT, Sout, LOG>(wA, pA, uA, outb, outg);
        emit<LOUT, Sout, LOG>(wB, pB, uB, outb, outg);
    }
}

__global__ __launch_bounds__(BT, 8) void dwt_quad(
    const float* __restrict__ x, float* __restrict__ y) {
    // ext strides (mult of 4, >= 2*LOUT+16 for b128 over-read)
    constexpr int S1 = 4140, S2 = 2092, S3 = 1068, S4 = 556;
    __shared__ __align__(16) float bufA[4272];   // input ext (4140) | stage2 out 4x1068
    __shared__ __align__(16) float bufB[4448];   // stage1 out 2x2092 | stage3 out 8x556

    const int m = blockIdx.x;
    const float* row = x + (size_t)m * 4112;

    // fill input ext: bufA[14+p] = row[p], p in [0,4110), mirrored margins
    for (int h = threadIdx.x; h < 2055; h += BT) {
        const int p = 2 * h;
        const float2 v = *reinterpret_cast<const float2*>(row + p);
        *reinterpret_cast<float2*>(&bufA[14 + p]) = v;
        if (p <= 14 || p >= 4110 - 16) {
            mirror_put(bufA, 4110, p, v.x);
            mirror_put(bufA, 4110, p + 1, v.y);
        }
    }
    __syncthreads();

    stage<4110, 1, S1, S2, false>(bufA, bufB, nullptr);  // -> 2 x 2062
    __syncthreads();
    stage<2062, 2, S2, S3, false>(bufB, bufA, nullptr);  // -> 4 x 1038
    __syncthreads();
    stage<1038, 4, S3, S4, false>(bufA, bufB, nullptr);  // -> 8 x 526
    __syncthreads();
    stage<526, 8, S4, 0, true>(bufB, nullptr, y + (size_t)m * 4320);  // 16 x 270
}

extern "C" void kernel_launch(void* const* d_in, const int* in_sizes, int n_in,
                              void* d_out, int out_size, void* d_ws, size_t ws_size,
                              hipStream_t stream) {
    const float* in = (const float*)d_in[0];
    float* out = (float*)d_out;
    float* wsA = (float*)d_ws;              // lev1: 512 rows, stride 16396
    float* wsB = (float*)d_ws + 8400000;    // lev3: 2048 rows, stride 4112
    (void)ws_size; (void)out_size; (void)n_in; (void)in_sizes;

    // F01: 65536 -> 32775 -> 16395; MB=1026, 16 segs
    { dim3 g(16, 128); dwt_pair<65536, 32775, 16395, 65536, 16396, 1026>
          <<<g, BT, 0, stream>>>(in, wsA); }
    // F23: 16395 -> 8205 -> 4110; MB=1028, 4 segs
    { dim3 g(4, 512);  dwt_pair<16395, 8205, 4110, 16396, 4112, 1028>
          <<<g, BT, 0, stream>>>(wsA, wsB); }
    // F47: 4110 -> 2062 -> 1038 -> 526 -> 270(+log)
    dwt_quad<<<2048, BT, 0, stream>>>(wsB, out);
}

// Round 12
// 98.758 us; speedup vs baseline: 4.8319x; 1.0258x over previous
//
#include <hip/hip_runtime.h>

// 8-level sym8 wavelet packet transform, B=128 rows of L0=65536, f32.
// 3 fused kernels: F01 (levels 0-1), F23 (levels 2-3), F47 (levels 4-7).
// Lengths: 65536->32775->16395->8205->4110->2062->1038->526->270.
// R6 geometry. R11: __launch_bounds__(512, 4) (128-VGPR cap instead of 64)
// so the 2-group pipelined quad stages can hold both 20-float windows in
// registers (R10's pairing was re-serialized at VGPR=28 under the (512,8)
// 64-VGPR cap). Pair kernels are R6-verbatim + relaxed bounds.

#define BT 512

// fl[t] = dec_lo[15-t]  (flipped low-pass, cross-correlation form)
__device__ __constant__ float FL[16] = {
     0.0018899503327594609f, -0.0003029205147213668f, -0.01495225833704823f,
     0.003808752013890615f,   0.049137179673607506f,  -0.027219029917056003f,
    -0.05194583810770904f,    0.3644418948353314f,     0.7771857517005235f,
     0.4813596512583722f,    -0.061273359067658524f,  -0.1432942383508097f,
     0.007607487324917605f,   0.03169508781149298f,   -0.0005421323317911481f,
    -0.0033824159510061256f
};

// fh[t] = dec_hi[15-t] = (t odd ? +1 : -1) * dec_lo[t]
__device__ __constant__ float FH[16] = {
     0.0033824159510061256f, -0.0005421323317911481f, -0.03169508781149298f,
     0.007607487324917605f,   0.1432942383508097f,    -0.061273359067658524f,
    -0.4813596512583722f,     0.7771857517005235f,    -0.3644418948353314f,
    -0.05194583810770904f,    0.027219029917056003f,   0.049137179673607506f,
    -0.003808752013890615f,  -0.01495225833704823f,    0.0003029205147213668f,
     0.0018899503327594609f
};

__device__ __forceinline__ int reflect(int q, int L) {
    q = (q < 0) ? -q : q;
    return (q >= L) ? (2 * L - 2 - q) : q;
}

// Mirror write into an ext buffer. ext = EXT BASE (genuine j lives at ext[14+j]).
__device__ __forceinline__ void mirror_put(float* ext, int LOUTc, int j, float v) {
    if (j >= 1 && j <= 14) ext[14 - j] = v;
    if (j >= LOUTc - 15 && j <= LOUTc - 2) ext[2 * LOUTc + 12 - j] = v;
}

// Load 20-float window from LDS: 5 x ds_read_b128 (base must be mult of 4).
__device__ __forceinline__ void load20(const float* __restrict__ lds, int base,
                                       float w[20]) {
#pragma unroll
    for (int k = 0; k < 5; ++k) {
        const float4 v = *reinterpret_cast<const float4*>(&lds[base + 4 * k]);
        w[4 * k] = v.x; w[4 * k + 1] = v.y; w[4 * k + 2] = v.z; w[4 * k + 3] = v.w;
    }
}

// Convolve positions (j, j+1) with both filters from an 18-tap window.
__device__ __forceinline__ void conv2(const float w[20], float& lo0, float& hi0,
                                      float& lo1, float& hi1) {
    lo0 = hi0 = lo1 = hi1 = 0.f;
#pragma unroll
    for (int t = 0; t < 16; ++t) {
        const float cl = FL[t], ch = FH[t];
        lo0 = fmaf(w[t], cl, lo0);
        hi0 = fmaf(w[t], ch, hi0);
        lo1 = fmaf(w[t + 2], cl, lo1);
        hi1 = fmaf(w[t + 2], ch, hi1);
    }
}

// ---------------- Fused two-level kernel (levels k, k+1) ----------------
template <int LIN, int LA, int LB, int SIN, int SOUT, int MB>
__global__ __launch_bounds__(BT, 4) void dwt_pair(
    const float* __restrict__ x, float* __restrict__ y) {
    constexpr int WA  = 2 * MB + 14;                 // virtual A-tile width (even)
    constexpr int WAp = (WA + 2 + 3) & ~3;           // subband stride (mult 4, +pad)
    constexpr int WX  = 2 * WA + 14;                 // x-tile width (even)
    constexpr int WXp = (WX + 2 + 3) & ~3;           // with b128 over-read pad
    constexpr int PP  = WA / 2;                      // A-phase pairs
    constexpr int GH  = MB / 2;                      // B-phase pairs per subband
    __shared__ __align__(16) float xs[WXp];
    __shared__ __align__(16) float as[2 * WAp];

    const int seg = blockIdx.x;
    const int n   = blockIdx.y;
    const int b0  = seg * MB;
    const int a_lo = 2 * b0 - 14;        // virtual tile start (may be <0 / >LA-WA)
    const int px0  = 2 * a_lo - 14;      // x coordinate of xs[0] (always even)

    const float* row = x + (size_t)n * (size_t)SIN;

    // ---- x-tile fill ----
    if (px0 >= 0 && px0 + WX <= LIN) {
        const float2* rp = reinterpret_cast<const float2*>(row + px0);
        for (int h = threadIdx.x; h < WX / 2; h += BT) {
            *reinterpret_cast<float2*>(&xs[2 * h]) = rp[h];
        }
    } else {
        for (int p = threadIdx.x; p < WX; p += BT) {
            xs[p] = row[reflect(px0 + p, LIN)];
        }
    }
    __syncthreads();

    // ---- A-phase: virtual positions a_lo+s, s in [0, WA) ----
    const int jbmax = ((b0 + MB < LB) ? (b0 + MB) : LB) - 1;
    const int smax  = 2 * (jbmax - b0) + 15;    // max tile-s read by B
    for (int g = threadIdx.x; g < PP; g += BT) {
        const int s0 = 2 * g;
        if (s0 > smax) continue;
        const int a  = a_lo + s0;
        float lo0, hi0, lo1, hi1;
        if (a >= 0 && a + 1 < LA) {
            float w[20];
            load20(xs, 4 * g, w);        // rel window = [2*s0, 2*s0+17]
            conv2(w, lo0, hi0, lo1, hi1);
        } else {
#pragma unroll
            for (int e = 0; e < 2; ++e) {
                const int ga = reflect(a + e, LA);
                const int bb = 2 * ga - 14 - px0;    // even, in-range
                float l = 0.f, h = 0.f;
#pragma unroll
                for (int t = 0; t < 16; ++t) {
                    const float v = xs[bb + t];
                    l = fmaf(v, FL[t], l);
                    h = fmaf(v, FH[t], h);
                }
                if (e == 0) { lo0 = l; hi0 = h; } else { lo1 = l; hi1 = h; }
            }
        }
        *reinterpret_cast<float2*>(&as[s0])       = make_float2(lo0, lo1);
        *reinterpret_cast<float2*>(&as[WAp + s0]) = make_float2(hi0, hi1);
    }
    __syncthreads();

    // ---- B-phase ----
    for (int g = threadIdx.x; g < 2 * GH; g += BT) {
        const int sA = (g >= GH) ? 1 : 0;
        const int u  = g - sA * GH;
        const int j0 = b0 + 2 * u;
        if (j0 >= LB) continue;
        float w[20];
        load20(as, sA * WAp + 4 * u, w);             // rel = q0 - a_lo = 4u
        float lo0, hi0, lo1, hi1;
        conv2(w, lo0, hi0, lo1, hi1);
        float* y0 = y + (size_t)(4 * n + 2 * sA) * (size_t)SOUT + (size_t)j0;
        float* y1 = y0 + SOUT;
        if (j0 + 1 < LB) {
            *reinterpret_cast<float2*>(y0) = make_float2(lo0, lo1);
            *reinterpret_cast<float2*>(y1) = make_float2(hi0, hi1);
        } else {
            y0[0] = lo0; y1[0] = hi0;
        }
    }
}

// ---------------- Fused four-level kernel (levels 4-7) ----------------
// ext layout per subrow: [14 reflected | L genuine | 14 reflected | pad]
template <int LOUT, int Sout, bool LOG>
__device__ __forceinline__ void emit(const float w[20], int p, int u,
                                     float* __restrict__ outb,
                                     float* __restrict__ outg) {
    float lo0, hi0, lo1, hi1;
    conv2(w, lo0, hi0, lo1, hi1);
    const int j0 = 2 * u;
    if (LOG) {
        float* o0 = outg + (size_t)(2 * p) * 270 + j0;
        float* o1 = o0 + 270;
        *reinterpret_cast<float2*>(o0) =
            make_float2(__logf(fmaf(lo0, lo0, 1e-12f)),
                        __logf(fmaf(lo1, lo1, 1e-12f)));
        *reinterpret_cast<float2*>(o1) =
            make_float2(__logf(fmaf(hi0, hi0, 1e-12f)),
                        __logf(fmaf(hi1, hi1, 1e-12f)));
    } else {
        float* e0 = outb + (2 * p) * Sout;       // EXT BASE pointers
        float* e1 = e0 + Sout;
        *reinterpret_cast<float2*>(e0 + 14 + j0) = make_float2(lo0, lo1);
        *reinterpret_cast<float2*>(e1 + 14 + j0) = make_float2(hi0, hi1);
        if (j0 <= 14 || j0 >= LOUT - 16) {
            mirror_put(e0, LOUT, j0, lo0);
            mirror_put(e0, LOUT, j0 + 1, lo1);
            mirror_put(e1, LOUT, j0, hi0);
            mirror_put(e1, LOUT, j0 + 1, hi1);
        }
    }
}

template <int L, int P, int Sin, int Sout, bool LOG>
__device__ __forceinline__ void stage(const float* __restrict__ inb,
                                      float* __restrict__ outb,
                                      float* __restrict__ outg) {
    constexpr int LOUT = L / 2 + 7;              // even for all our stages
    constexpr int PP   = LOUT / 2;
    constexpr int G    = P * PP;
    for (int g = threadIdx.x; g < G; g += 2 * BT) {
        const int gB = (g + BT < G) ? (g + BT) : (G - 1);
        int pA, uA, pB, uB;
        if constexpr (P == 1) {
            pA = 0; uA = g; pB = 0; uB = gB;
        } else {
            pA = g / PP;  uA = g - pA * PP;      // compile-time divisor
            pB = gB / PP; uB = gB - pB * PP;
        }
        float wA[20], wB[20];
        load20(inb, pA * Sin + 4 * uA, wA);      // both loads in flight
        load20(inb, pB * Sin + 4 * uB, wB);
        emit<LOUT, Sout, LOG>(wA, pA, uA, outb, outg);
        emit<LOUT, Sout, LOG>(wB, pB, uB, outb, outg);
    }
}

__global__ __launch_bounds__(BT, 4) void dwt_quad(
    const float* __restrict__ x, float* __restrict__ y) {
    // ext strides (mult of 4, >= 2*LOUT+16 for b128 over-read)
    constexpr int S1 = 4140, S2 = 2092, S3 = 1068, S4 = 556;
    __shared__ __align__(16) float bufA[4272];   // input ext (4140) | stage2 out 4x1068
    __shared__ __align__(16) float bufB[4448];   // stage1 out 2x2092 | stage3 out 8x556

    const int m = blockIdx.x;
    const float* row = x + (size_t)m * 4112;

    // fill input ext: bufA[14+p] = row[p], p in [0,4110), mirrored margins
    for (int h = threadIdx.x; h < 2055; h += BT) {
        const int p = 2 * h;
        const float2 v = *reinterpret_cast<const float2*>(row + p);
        *reinterpret_cast<float2*>(&bufA[14 + p]) = v;
        if (p <= 14 || p >= 4110 - 16) {
            mirror_put(bufA, 4110, p, v.x);
            mirror_put(bufA, 4110, p + 1, v.y);
        }
    }
    __syncthreads();

    stage<4110, 1, S1, S2, false>(bufA, bufB, nullptr);  // -> 2 x 2062
    __syncthreads();
    stage<2062, 2, S2, S3, false>(bufB, bufA, nullptr);  // -> 4 x 1038
    __syncthreads();
    stage<1038, 4, S3, S4, false>(bufA, bufB, nullptr);  // -> 8 x 526
    __syncthreads();
    stage<526, 8, S4, 0, true>(bufB, nullptr, y + (size_t)m * 4320);  // 16 x 270
}

extern "C" void kernel_launch(void* const* d_in, const int* in_sizes, int n_in,
                              void* d_out, int out_size, void* d_ws, size_t ws_size,
                              hipStream_t stream) {
    const float* in = (const float*)d_in[0];
    float* out = (float*)d_out;
    float* wsA = (float*)d_ws;              // lev1: 512 rows, stride 16396
    float* wsB = (float*)d_ws + 8400000;    // lev3: 2048 rows, stride 4112
    (void)ws_size; (void)out_size; (void)n_in; (void)in_sizes;

    // F01: 65536 -> 32775 -> 16395; MB=1026, 16 segs
    { dim3 g(16, 128); dwt_pair<65536, 32775, 16395, 65536, 16396, 1026>
          <<<g, BT, 0, stream>>>(in, wsA); }
    // F23: 16395 -> 8205 -> 4110; MB=1028, 4 segs
    { dim3 g(4, 512);  dwt_pair<16395, 8205, 4110, 16396, 4112, 1028>
          <<<g, BT, 0, stream>>>(wsA, wsB); }
    // F47: 4110 -> 2062 -> 1038 -> 526 -> 270(+log)
    dwt_quad<<<2048, BT, 0, stream>>>(wsB, out);
}

// Round 13
// 96.403 us; speedup vs baseline: 4.9499x; 1.0244x over previous
//
#include <hip/hip_runtime.h>

// 8-level sym8 wavelet packet transform, B=128 rows of L0=65536, f32.
// F01/F23: R6-proven dwt_pair (NO=2, virtual A-tile). F47 (dwt_quad8):
// NO=8 sliding-register window: 8 consecutive outputs/thread from a 32-float
// window read as 8x ds_read_b128; ext buffers live in a PADDED physical
// space P(i) = i + 4*(i>>6) (4-float pad per 64) so the 64-float lane stride
// becomes a 2-way (free) bank pattern. Subrow logical strides are multiples
// of 64 so window blocks never cross a pad. 256 thr, launch_bounds(256,4).

#define BTP 512   // pair kernels
#define BTQ 256   // quad kernel
#define PD(i) ((i) + (((i) >> 6) << 2))

// fl[t] = dec_lo[15-t]  (flipped low-pass, cross-correlation form)
__device__ __constant__ float FL[16] = {
     0.0018899503327594609f, -0.0003029205147213668f, -0.01495225833704823f,
     0.003808752013890615f,   0.049137179673607506f,  -0.027219029917056003f,
    -0.05194583810770904f,    0.3644418948353314f,     0.7771857517005235f,
     0.4813596512583722f,    -0.061273359067658524f,  -0.1432942383508097f,
     0.007607487324917605f,   0.03169508781149298f,   -0.0005421323317911481f,
    -0.0033824159510061256f
};

// fh[t] = dec_hi[15-t] = (t odd ? +1 : -1) * dec_lo[t]
__device__ __constant__ float FH[16] = {
     0.0033824159510061256f, -0.0005421323317911481f, -0.03169508781149298f,
     0.007607487324917605f,   0.1432942383508097f,    -0.061273359067658524f,
    -0.4813596512583722f,     0.7771857517005235f,    -0.3644418948353314f,
    -0.05194583810770904f,    0.027219029917056003f,   0.049137179673607506f,
    -0.003808752013890615f,  -0.01495225833704823f,    0.0003029205147213668f,
     0.0018899503327594609f
};

__device__ __forceinline__ int reflect(int q, int L) {
    q = (q < 0) ? -q : q;
    return (q >= L) ? (2 * L - 2 - q) : q;
}

// ======================= R6 pair kernels (verbatim) =======================
__device__ __forceinline__ void mirror_put(float* ext, int LOUTc, int j, float v) {
    if (j >= 1 && j <= 14) ext[14 - j] = v;
    if (j >= LOUTc - 15 && j <= LOUTc - 2) ext[2 * LOUTc + 12 - j] = v;
}

__device__ __forceinline__ void load20(const float* __restrict__ lds, int base,
                                       float w[20]) {
#pragma unroll
    for (int k = 0; k < 5; ++k) {
        const float4 v = *reinterpret_cast<const float4*>(&lds[base + 4 * k]);
        w[4 * k] = v.x; w[4 * k + 1] = v.y; w[4 * k + 2] = v.z; w[4 * k + 3] = v.w;
    }
}

__device__ __forceinline__ void conv2(const float w[20], float& lo0, float& hi0,
                                      float& lo1, float& hi1) {
    lo0 = hi0 = lo1 = hi1 = 0.f;
#pragma unroll
    for (int t = 0; t < 16; ++t) {
        const float cl = FL[t], ch = FH[t];
        lo0 = fmaf(w[t], cl, lo0);
        hi0 = fmaf(w[t], ch, hi0);
        lo1 = fmaf(w[t + 2], cl, lo1);
        hi1 = fmaf(w[t + 2], ch, hi1);
    }
}

template <int LIN, int LA, int LB, int SIN, int SOUT, int MB>
__global__ __launch_bounds__(BTP, 8) void dwt_pair(
    const float* __restrict__ x, float* __restrict__ y) {
    constexpr int WA  = 2 * MB + 14;
    constexpr int WAp = (WA + 2 + 3) & ~3;
    constexpr int WX  = 2 * WA + 14;
    constexpr int WXp = (WX + 2 + 3) & ~3;
    constexpr int PP  = WA / 2;
    constexpr int GH  = MB / 2;
    __shared__ __align__(16) float xs[WXp];
    __shared__ __align__(16) float as[2 * WAp];

    const int seg = blockIdx.x;
    const int n   = blockIdx.y;
    const int b0  = seg * MB;
    const int a_lo = 2 * b0 - 14;
    const int px0  = 2 * a_lo - 14;

    const float* row = x + (size_t)n * (size_t)SIN;

    if (px0 >= 0 && px0 + WX <= LIN) {
        const float2* rp = reinterpret_cast<const float2*>(row + px0);
        for (int h = threadIdx.x; h < WX / 2; h += BTP) {
            *reinterpret_cast<float2*>(&xs[2 * h]) = rp[h];
        }
    } else {
        for (int p = threadIdx.x; p < WX; p += BTP) {
            xs[p] = row[reflect(px0 + p, LIN)];
        }
    }
    __syncthreads();

    const int jbmax = ((b0 + MB < LB) ? (b0 + MB) : LB) - 1;
    const int smax  = 2 * (jbmax - b0) + 15;
    for (int g = threadIdx.x; g < PP; g += BTP) {
        const int s0 = 2 * g;
        if (s0 > smax) continue;
        const int a  = a_lo + s0;
        float lo0, hi0, lo1, hi1;
        if (a >= 0 && a + 1 < LA) {
            float w[20];
            load20(xs, 4 * g, w);
            conv2(w, lo0, hi0, lo1, hi1);
        } else {
#pragma unroll
            for (int e = 0; e < 2; ++e) {
                const int ga = reflect(a + e, LA);
                const int bb = 2 * ga - 14 - px0;
                float l = 0.f, h = 0.f;
#pragma unroll
                for (int t = 0; t < 16; ++t) {
                    const float v = xs[bb + t];
                    l = fmaf(v, FL[t], l);
                    h = fmaf(v, FH[t], h);
                }
                if (e == 0) { lo0 = l; hi0 = h; } else { lo1 = l; hi1 = h; }
            }
        }
        *reinterpret_cast<float2*>(&as[s0])       = make_float2(lo0, lo1);
        *reinterpret_cast<float2*>(&as[WAp + s0]) = make_float2(hi0, hi1);
    }
    __syncthreads();

    for (int g = threadIdx.x; g < 2 * GH; g += BTP) {
        const int sA = (g >= GH) ? 1 : 0;
        const int u  = g - sA * GH;
        const int j0 = b0 + 2 * u;
        if (j0 >= LB) continue;
        float w[20];
        load20(as, sA * WAp + 4 * u, w);
        float lo0, hi0, lo1, hi1;
        conv2(w, lo0, hi0, lo1, hi1);
        float* y0 = y + (size_t)(4 * n + 2 * sA) * (size_t)SOUT + (size_t)j0;
        float* y1 = y0 + SOUT;
        if (j0 + 1 < LB) {
            *reinterpret_cast<float2*>(y0) = make_float2(lo0, lo1);
            *reinterpret_cast<float2*>(y1) = make_float2(hi0, hi1);
        } else {
            y0[0] = lo0; y1[0] = hi0;
        }
    }
}

// ================== Quad kernel: NO=8 + padded bank swizzle ==================
// ext logical layout per subrow (stride SL, SL % 64 == 0):
//   [14 left margin | L genuine | 14 right margin | slack]
// position p lives at logical 14+p; physical index = PD(logical).
// Taps for output j: logical 2j+t (t=0..15); group j0=8v reads logical
// [16v, 16v+31] as two 16-float blocks (never cross a pad).
template <int Lin, int Pn, int SLin, int SLout, bool LOG>
__device__ __forceinline__ void stage8(const float* __restrict__ inb,
                                       float* __restrict__ outb,
                                       float* __restrict__ outg) {
    constexpr int LOUT = Lin / 2 + 7;           // even for all our stages
    constexpr int GP   = (LOUT + 7) / 8;
    constexpr int G    = Pn * GP;
    for (int g = threadIdx.x; g < G; g += BTQ) {
        const int p  = g / GP;                  // compile-time divisor
        const int v  = g - p * GP;
        const int j0 = 8 * v;
        const int baseL = p * SLin + 16 * v;    // logical window base

        float w[32];
        {
            const int phA = PD(baseL);
            const int phB = PD(baseL + 16);
#pragma unroll
            for (int k = 0; k < 4; ++k)
                *reinterpret_cast<float4*>(&w[4 * k]) =
                    *reinterpret_cast<const float4*>(&inb[phA + 4 * k]);
#pragma unroll
            for (int k = 0; k < 4; ++k)
                *reinterpret_cast<float4*>(&w[16 + 4 * k]) =
                    *reinterpret_cast<const float4*>(&inb[phB + 4 * k]);
        }

        float lo[8], hi[8];
#pragma unroll
        for (int d = 0; d < 8; ++d) { lo[d] = 0.f; hi[d] = 0.f; }
#pragma unroll
        for (int t = 0; t < 16; ++t) {
            const float cl = FL[t], ch = FH[t];
#pragma unroll
            for (int d = 0; d < 8; ++d) {
                const float vv = w[2 * d + t];
                lo[d] = fmaf(vv, cl, lo[d]);
                hi[d] = fmaf(vv, ch, hi[d]);
            }
        }

        if (LOG) {
            float* y0 = outg + (2 * p) * 270;
            float* y1 = y0 + 270;
#pragma unroll
            for (int k = 0; k < 4; ++k) {
                const int j = j0 + 2 * k;
                if (j < 270) {
                    *reinterpret_cast<float2*>(y0 + j) =
                        make_float2(__logf(fmaf(lo[2 * k], lo[2 * k], 1e-12f)),
                                    __logf(fmaf(lo[2 * k + 1], lo[2 * k + 1], 1e-12f)));
                    *reinterpret_cast<float2*>(y1 + j) =
                        make_float2(__logf(fmaf(hi[2 * k], hi[2 * k], 1e-12f)),
                                    __logf(fmaf(hi[2 * k + 1], hi[2 * k + 1], 1e-12f)));
                }
            }
        } else {
            const int b0L = (2 * p) * SLout;        // lo subrow logical base
            const int b1L = (2 * p + 1) * SLout;    // hi subrow logical base
#pragma unroll
            for (int k = 0; k < 4; ++k) {
                const int j = j0 + 2 * k;
                if (j < LOUT) {
                    *reinterpret_cast<float2*>(&outb[PD(b0L + 14 + j)]) =
                        make_float2(lo[2 * k], lo[2 * k + 1]);
                    *reinterpret_cast<float2*>(&outb[PD(b1L + 14 + j)]) =
                        make_float2(hi[2 * k], hi[2 * k + 1]);
                }
            }
            if (j0 <= 14) {                          // left margin sources j in [1,14]
#pragma unroll
                for (int d = 0; d < 8; ++d) {
                    const int j = j0 + d;
                    if (j >= 1 && j <= 14) {
                        outb[PD(b0L + 14 - j)] = lo[d];
                        outb[PD(b1L + 14 - j)] = hi[d];
                    }
                }
            }
            if (j0 >= LOUT - 24) {                   // right margin sources
#pragma unroll
                for (int d = 0; d < 8; ++d) {
                    const int j = j0 + d;
                    if (j >= LOUT - 15 && j <= LOUT - 2) {
                        outb[PD(b0L + 14 + 2 * LOUT - 2 - j)] = lo[d];
                        outb[PD(b1L + 14 + 2 * LOUT - 2 - j)] = hi[d];
                    }
                }
            }
        }
    }
}

__global__ __launch_bounds__(BTQ, 4) void dwt_quad8(
    const float* __restrict__ x, float* __restrict__ y) {
    // logical strides (x64): in 4160, lev4 2112, lev5 1088, lev6 576
    // physical spans: in 4420 | lev5 4624 ; lev4 4488 | lev6 4896
    __shared__ __align__(16) float bufA[4624];
    __shared__ __align__(16) float bufB[4896];

    const int m = blockIdx.x;
    const float* row = x + (size_t)m * 4112;
    const float2* rp = reinterpret_cast<const float2*>(row);

    // fill input ext: logical 14+p = row[p], p in [0,4110)
    for (int i = threadIdx.x; i < 2055; i += BTQ) {
        *reinterpret_cast<float2*>(&bufA[PD(14 + 2 * i)]) = rp[i];
    }
    {
        const int t = threadIdx.x;
        if (t < 14) {
            bufA[PD(13 - t)] = row[1 + t];                  // left: pos -(1+t)
        } else if (t < 28) {
            const int p = 4110 + (t - 14);                  // right: pos p
            bufA[PD(14 + p)] = row[8218 - p];               // 2*4110-2-p
        }
    }
    __syncthreads();

    stage8<4110, 1, 4160, 2112, false>(bufA, bufB, nullptr);  // -> 2 x 2062
    __syncthreads();
    stage8<2062, 2, 2112, 1088, false>(bufB, bufA, nullptr);  // -> 4 x 1038
    __syncthreads();
    stage8<1038, 4, 1088, 576, false>(bufA, bufB, nullptr);   // -> 8 x 526
    __syncthreads();
    stage8<526, 8, 576, 0, true>(bufB, nullptr, y + (size_t)m * 4320); // 16x270
}

extern "C" void kernel_launch(void* const* d_in, const int* in_sizes, int n_in,
                              void* d_out, int out_size, void* d_ws, size_t ws_size,
                              hipStream_t stream) {
    const float* in = (const float*)d_in[0];
    float* out = (float*)d_out;
    float* wsA = (float*)d_ws;              // lev1: 512 rows, stride 16396
    float* wsB = (float*)d_ws + 8400000;    // lev3: 2048 rows, stride 4112
    (void)ws_size; (void)out_size; (void)n_in; (void)in_sizes;

    // F01: 65536 -> 32775 -> 16395; MB=1026, 16 segs
    { dim3 g(16, 128); dwt_pair<65536, 32775, 16395, 65536, 16396, 1026>
          <<<g, BTP, 0, stream>>>(in, wsA); }
    // F23: 16395 -> 8205 -> 4110; MB=1028, 4 segs
    { dim3 g(4, 512);  dwt_pair<16395, 8205, 4110, 16396, 4112, 1028>
          <<<g, BTP, 0, stream>>>(wsA, wsB); }
    // F47: 4110 -> 2062 -> 1038 -> 526 -> 270(+log)
    dwt_quad8<<<2048, BTQ, 0, stream>>>(wsB, out);
}

// Round 14
// 88.980 us; speedup vs baseline: 5.3629x; 1.0834x over previous
//
#include <hip/hip_runtime.h>

// 8-level sym8 wavelet packet transform, B=128 rows of L0=65536, f32.
// Best-of assembly: R6 dwt_pair for F01/F23 (measured 47.1 us combined) +
// R7 polyphase dwt_quad_eo for F47 (measured 40.6 us). Both verbatim.
// Lengths: 65536->32775->16395->8205->4110->2062->1038->526->270.

#define BT 512

// fl[t] = dec_lo[15-t]  (flipped low-pass, cross-correlation form)
__device__ __constant__ float FL[16] = {
     0.0018899503327594609f, -0.0003029205147213668f, -0.01495225833704823f,
     0.003808752013890615f,   0.049137179673607506f,  -0.027219029917056003f,
    -0.05194583810770904f,    0.3644418948353314f,     0.7771857517005235f,
     0.4813596512583722f,    -0.061273359067658524f,  -0.1432942383508097f,
     0.007607487324917605f,   0.03169508781149298f,   -0.0005421323317911481f,
    -0.0033824159510061256f
};

// fh[t] = dec_hi[15-t] = (t odd ? +1 : -1) * dec_lo[t]
__device__ __constant__ float FH[16] = {
     0.0033824159510061256f, -0.0005421323317911481f, -0.03169508781149298f,
     0.007607487324917605f,   0.1432942383508097f,    -0.061273359067658524f,
    -0.4813596512583722f,     0.7771857517005235f,    -0.3644418948353314f,
    -0.05194583810770904f,    0.027219029917056003f,   0.049137179673607506f,
    -0.003808752013890615f,  -0.01495225833704823f,    0.0003029205147213668f,
     0.0018899503327594609f
};

// Even/odd split of the flipped dec filters (for the polyphase quad).
__device__ __constant__ float FLE[8] = {
     0.0018899503327594609f, -0.01495225833704823f,  0.049137179673607506f,
    -0.05194583810770904f,   0.7771857517005235f,   -0.061273359067658524f,
     0.007607487324917605f, -0.0005421323317911481f };
__device__ __constant__ float FLO[8] = {
    -0.0003029205147213668f, 0.003808752013890615f, -0.027219029917056003f,
     0.3644418948353314f,    0.4813596512583722f,   -0.1432942383508097f,
     0.03169508781149298f,  -0.0033824159510061256f };
__device__ __constant__ float FHE[8] = {
     0.0033824159510061256f, -0.03169508781149298f,  0.1432942383508097f,
    -0.4813596512583722f,   -0.3644418948353314f,    0.027219029917056003f,
    -0.003808752013890615f,  0.0003029205147213668f };
__device__ __constant__ float FHO[8] = {
    -0.0005421323317911481f, 0.007607487324917605f, -0.061273359067658524f,
     0.7771857517005235f,   -0.05194583810770904f,   0.049137179673607506f,
    -0.01495225833704823f,   0.0018899503327594609f };

__device__ __forceinline__ int reflect(int q, int L) {
    q = (q < 0) ? -q : q;
    return (q >= L) ? (2 * L - 2 - q) : q;
}

// ======================= R6 pair kernel (verbatim) =======================
__device__ __forceinline__ void load20(const float* __restrict__ lds, int base,
                                       float w[20]) {
#pragma unroll
    for (int k = 0; k < 5; ++k) {
        const float4 v = *reinterpret_cast<const float4*>(&lds[base + 4 * k]);
        w[4 * k] = v.x; w[4 * k + 1] = v.y; w[4 * k + 2] = v.z; w[4 * k + 3] = v.w;
    }
}

__device__ __forceinline__ void conv2(const float w[20], float& lo0, float& hi0,
                                      float& lo1, float& hi1) {
    lo0 = hi0 = lo1 = hi1 = 0.f;
#pragma unroll
    for (int t = 0; t < 16; ++t) {
        const float cl = FL[t], ch = FH[t];
        lo0 = fmaf(w[t], cl, lo0);
        hi0 = fmaf(w[t], ch, hi0);
        lo1 = fmaf(w[t + 2], cl, lo1);
        hi1 = fmaf(w[t + 2], ch, hi1);
    }
}

template <int LIN, int LA, int LB, int SIN, int SOUT, int MB>
__global__ __launch_bounds__(BT, 8) void dwt_pair(
    const float* __restrict__ x, float* __restrict__ y) {
    constexpr int WA  = 2 * MB + 14;
    constexpr int WAp = (WA + 2 + 3) & ~3;
    constexpr int WX  = 2 * WA + 14;
    constexpr int WXp = (WX + 2 + 3) & ~3;
    constexpr int PP  = WA / 2;
    constexpr int GH  = MB / 2;
    __shared__ __align__(16) float xs[WXp];
    __shared__ __align__(16) float as[2 * WAp];

    const int seg = blockIdx.x;
    const int n   = blockIdx.y;
    const int b0  = seg * MB;
    const int a_lo = 2 * b0 - 14;
    const int px0  = 2 * a_lo - 14;

    const float* row = x + (size_t)n * (size_t)SIN;

    if (px0 >= 0 && px0 + WX <= LIN) {
        const float2* rp = reinterpret_cast<const float2*>(row + px0);
        for (int h = threadIdx.x; h < WX / 2; h += BT) {
            *reinterpret_cast<float2*>(&xs[2 * h]) = rp[h];
        }
    } else {
        for (int p = threadIdx.x; p < WX; p += BT) {
            xs[p] = row[reflect(px0 + p, LIN)];
        }
    }
    __syncthreads();

    const int jbmax = ((b0 + MB < LB) ? (b0 + MB) : LB) - 1;
    const int smax  = 2 * (jbmax - b0) + 15;
    for (int g = threadIdx.x; g < PP; g += BT) {
        const int s0 = 2 * g;
        if (s0 > smax) continue;
        const int a  = a_lo + s0;
        float lo0, hi0, lo1, hi1;
        if (a >= 0 && a + 1 < LA) {
            float w[20];
            load20(xs, 4 * g, w);
            conv2(w, lo0, hi0, lo1, hi1);
        } else {
#pragma unroll
            for (int e = 0; e < 2; ++e) {
                const int ga = reflect(a + e, LA);
                const int bb = 2 * ga - 14 - px0;
                float l = 0.f, h = 0.f;
#pragma unroll
                for (int t = 0; t < 16; ++t) {
                    const float v = xs[bb + t];
                    l = fmaf(v, FL[t], l);
                    h = fmaf(v, FH[t], h);
                }
                if (e == 0) { lo0 = l; hi0 = h; } else { lo1 = l; hi1 = h; }
            }
        }
        *reinterpret_cast<float2*>(&as[s0])       = make_float2(lo0, lo1);
        *reinterpret_cast<float2*>(&as[WAp + s0]) = make_float2(hi0, hi1);
    }
    __syncthreads();

    for (int g = threadIdx.x; g < 2 * GH; g += BT) {
        const int sA = (g >= GH) ? 1 : 0;
        const int u  = g - sA * GH;
        const int j0 = b0 + 2 * u;
        if (j0 >= LB) continue;
        float w[20];
        load20(as, sA * WAp + 4 * u, w);
        float lo0, hi0, lo1, hi1;
        conv2(w, lo0, hi0, lo1, hi1);
        float* y0 = y + (size_t)(4 * n + 2 * sA) * (size_t)SOUT + (size_t)j0;
        float* y1 = y0 + SOUT;
        if (j0 + 1 < LB) {
            *reinterpret_cast<float2*>(y0) = make_float2(lo0, lo1);
            *reinterpret_cast<float2*>(y1) = make_float2(hi0, hi1);
        } else {
            y0[0] = lo0; y1[0] = hi0;
        }
    }
}

// ================= R7 polyphase quad kernel (verbatim) =================
__device__ __forceinline__ void eo_put(float* __restrict__ E, float* __restrict__ O,
                                       int q, float v) {
    ((q & 1) ? O : E)[8 + (q >> 1)] = v;
}

__device__ __forceinline__ void read12(const float* __restrict__ b, int w0,
                                       float* __restrict__ r) {
#pragma unroll
    for (int k = 0; k < 3; ++k) {
        const float4 v = *reinterpret_cast<const float4*>(&b[w0 + 4 * k]);
        r[4 * k] = v.x; r[4 * k + 1] = v.y; r[4 * k + 2] = v.z; r[4 * k + 3] = v.w;
    }
}

template <int OFF>
__device__ __forceinline__ void conv4eo(const float e[12], const float o[12],
                                        float lo[4], float hi[4]) {
#pragma unroll
    for (int d = 0; d < 4; ++d) { lo[d] = 0.f; hi[d] = 0.f; }
#pragma unroll
    for (int s = 0; s < 8; ++s) {
        const float fle = FLE[s], flo = FLO[s], fhe = FHE[s], fho = FHO[s];
#pragma unroll
        for (int d = 0; d < 4; ++d) {
            const float ev = e[OFF + d + s], ov = o[OFF + d + s];
            lo[d] = fmaf(ev, fle, lo[d]);
            lo[d] = fmaf(ov, flo, lo[d]);
            hi[d] = fmaf(ev, fhe, hi[d]);
            hi[d] = fmaf(ov, fho, hi[d]);
        }
    }
}

// Subband ext layout: [E: 8 margin | H | 12 margin+pad][O: same], stride Sin/2.
template <int Ls, int P, int Sin, int Sout, bool LOG>
__device__ __forceinline__ void stage_eo(const float* __restrict__ inb,
                                         float* __restrict__ outb,
                                         float* __restrict__ outg) {
    constexpr int H    = Ls / 2;
    constexpr int LOUT = H + 7;                 // even for all our stages
    constexpr int GPS  = (LOUT + 3) / 4;
    constexpr int SEi  = Sin / 2;
    constexpr int SEo  = Sout / 2;
    for (int g = threadIdx.x; g < P * GPS; g += BT) {
        const int p  = g / GPS;                 // compile-time divisor
        const int u  = g - p * GPS;
        const int j0 = 4 * u;
        const float* Ei = inb + p * Sin;
        const float* Oi = Ei + SEi;
        float e[12], o[12];
        read12(Ei, 4 * u, e);                   // ext words 4u..4u+11 (idx j0-8..j0+3)
        read12(Oi, 4 * u, o);
        float lo[4], hi[4];
        conv4eo<1>(e, o, lo, hi);
        if (LOG) {
            float r0[4], r1[4];
#pragma unroll
            for (int d = 0; d < 4; ++d) {
                r0[d] = __logf(fmaf(lo[d], lo[d], 1e-12f));
                r1[d] = __logf(fmaf(hi[d], hi[d], 1e-12f));
            }
            float* y0 = outg + (2 * p) * 270 + j0;
            float* y1 = y0 + 270;
            if (j0 + 3 < 270) {
                *reinterpret_cast<float2*>(y0)     = make_float2(r0[0], r0[1]);
                *reinterpret_cast<float2*>(y0 + 2) = make_float2(r0[2], r0[3]);
                *reinterpret_cast<float2*>(y1)     = make_float2(r1[0], r1[1]);
                *reinterpret_cast<float2*>(y1 + 2) = make_float2(r1[2], r1[3]);
            } else {                            // 270 % 4 == 2: exactly 2 valid
                *reinterpret_cast<float2*>(y0) = make_float2(r0[0], r0[1]);
                *reinterpret_cast<float2*>(y1) = make_float2(r1[0], r1[1]);
            }
        } else {
            float* El = outb + (2 * p) * Sout;
            float* Ol = El + SEo;
            float* Eh = outb + (2 * p + 1) * Sout;
            float* Oh = Eh + SEo;
            if (j0 + 3 < LOUT) {                // main: dense b64 writes
                *reinterpret_cast<float2*>(&El[8 + 2 * u]) = make_float2(lo[0], lo[2]);
                *reinterpret_cast<float2*>(&Ol[8 + 2 * u]) = make_float2(lo[1], lo[3]);
                *reinterpret_cast<float2*>(&Eh[8 + 2 * u]) = make_float2(hi[0], hi[2]);
                *reinterpret_cast<float2*>(&Oh[8 + 2 * u]) = make_float2(hi[1], hi[3]);
            } else {                            // last group: guarded scalar
#pragma unroll
                for (int d = 0; d < 4; ++d)
                    if (j0 + d < LOUT) {
                        eo_put(El, Ol, j0 + d, lo[d]);
                        eo_put(Eh, Oh, j0 + d, hi[d]);
                    }
            }
            if (j0 <= 14 || j0 >= LOUT - 18) {  // margin mirror writes
#pragma unroll
                for (int d = 0; d < 4; ++d) {
                    const int j = j0 + d;
                    if (j >= 1 && j <= 14) {
                        eo_put(El, Ol, -j, lo[d]);
                        eo_put(Eh, Oh, -j, hi[d]);
                    }
                    if (j >= LOUT - 15 && j <= LOUT - 2) {
                        eo_put(El, Ol, 2 * LOUT - 2 - j, lo[d]);
                        eo_put(Eh, Oh, 2 * LOUT - 2 - j, hi[d]);
                    }
                }
            }
        }
    }
}

__global__ __launch_bounds__(BT, 8) void dwt_quad_eo(
    const float* __restrict__ x, float* __restrict__ y) {
    // SE strides: L=4110:2076 L=2062:1052 L=1038:540 L=526:284 (all mult 4)
    __shared__ __align__(16) float bufA[4320];  // in 4152 | s2-out 4x1080
    __shared__ __align__(16) float bufB[4544];  // s1-out 2x2104 | s3-out 8x568

    const int m = blockIdx.x;
    const float* row = x + (size_t)m * 4112;
    float* Ex = bufA;
    float* Ox = bufA + 2076;
    for (int i = threadIdx.x; i < 2055; i += BT) {
        const float2 v = reinterpret_cast<const float2*>(row)[i];
        Ex[8 + i] = v.x;
        Ox[8 + i] = v.y;
        if (i >= 1 && i <= 7)       eo_put(Ex, Ox, -2 * i, v.x);          // x[2i] -> -2i
        if (i <= 6)                 eo_put(Ex, Ox, -(2 * i + 1), v.y);    // x[2i+1]
        if (i >= 2048)              eo_put(Ex, Ox, 8218 - 2 * i, v.x);    // 2*4110-2-p
        if (i >= 2047 && i <= 2053) eo_put(Ex, Ox, 8217 - 2 * i, v.y);
    }
    __syncthreads();
    stage_eo<4110, 1, 4152, 2104, false>(bufA, bufB, nullptr);  // -> 2x2062
    __syncthreads();
    stage_eo<2062, 2, 2104, 1080, false>(bufB, bufA, nullptr);  // -> 4x1038
    __syncthreads();
    stage_eo<1038, 4, 1080, 568, false>(bufA, bufB, nullptr);   // -> 8x526
    __syncthreads();
    stage_eo<526, 8, 568, 0, true>(bufB, nullptr, y + (size_t)m * 4320); // 16x270
}

extern "C" void kernel_launch(void* const* d_in, const int* in_sizes, int n_in,
                              void* d_out, int out_size, void* d_ws, size_t ws_size,
                              hipStream_t stream) {
    const float* in = (const float*)d_in[0];
    float* out = (float*)d_out;
    float* wsA = (float*)d_ws;              // lev1: 512 rows, stride 16396
    float* wsB = (float*)d_ws + 8400000;    // lev3: 2048 rows, stride 4112
    (void)ws_size; (void)out_size; (void)n_in; (void)in_sizes;

    // F01: 65536 -> 32775 -> 16395; MB=1026, 16 segs
    { dim3 g(16, 128); dwt_pair<65536, 32775, 16395, 65536, 16396, 1026>
          <<<g, BT, 0, stream>>>(in, wsA); }
    // F23: 16395 -> 8205 -> 4110; MB=1028, 4 segs
    { dim3 g(4, 512);  dwt_pair<16395, 8205, 4110, 16396, 4112, 1028>
          <<<g, BT, 0, stream>>>(wsA, wsB); }
    // F47: 4110 -> 2062 -> 1038 -> 526 -> 270(+log)
    dwt_quad_eo<<<2048, BT, 0, stream>>>(wsB, out);
}

// Round 15
// 74.025 us; speedup vs baseline: 6.4463x; 1.2020x over previous
//
#include <hip/hip_runtime.h>

// 8-level sym8 wavelet packet transform, B=128 rows of L0=65536, f32.
// TWO kernels: dwt_f03 (levels 0-3, segmented virtual-tile LDS chain) +
// dwt_quad_eo (levels 4-7, R7 polyphase, whole-subrow LDS).
// Lengths: 65536->32775->16395->8205->4110->2062->1038->526->270.
// F03: block = (seg of 258 lev3-positions, row). All intermediates are
// VIRTUAL tiles (slot q holds value at reflect(q,L)) so consumer reads are
// blind dense load20 at base 4u; edge groups (segs 0/15 only) recompute at
// the reflected position via scalar windows (operands proven in-tile).
// Anchors: a2=2*b0-14, c1=4*b0-42, a0=8*b0-98, px0=16*b0-210.

#define BT 512

// fl[t] = dec_lo[15-t]  (flipped low-pass, cross-correlation form)
__device__ __constant__ float FL[16] = {
     0.0018899503327594609f, -0.0003029205147213668f, -0.01495225833704823f,
     0.003808752013890615f,   0.049137179673607506f,  -0.027219029917056003f,
    -0.05194583810770904f,    0.3644418948353314f,     0.7771857517005235f,
     0.4813596512583722f,    -0.061273359067658524f,  -0.1432942383508097f,
     0.007607487324917605f,   0.03169508781149298f,   -0.0005421323317911481f,
    -0.0033824159510061256f
};

// fh[t] = dec_hi[15-t] = (t odd ? +1 : -1) * dec_lo[t]
__device__ __constant__ float FH[16] = {
     0.0033824159510061256f, -0.0005421323317911481f, -0.03169508781149298f,
     0.007607487324917605f,   0.1432942383508097f,    -0.061273359067658524f,
    -0.4813596512583722f,     0.7771857517005235f,    -0.3644418948353314f,
    -0.05194583810770904f,    0.027219029917056003f,   0.049137179673607506f,
    -0.003808752013890615f,  -0.01495225833704823f,    0.0003029205147213668f,
     0.0018899503327594609f
};

// Even/odd split of the flipped dec filters (for the polyphase quad).
__device__ __constant__ float FLE[8] = {
     0.0018899503327594609f, -0.01495225833704823f,  0.049137179673607506f,
    -0.05194583810770904f,   0.7771857517005235f,   -0.061273359067658524f,
     0.007607487324917605f, -0.0005421323317911481f };
__device__ __constant__ float FLO[8] = {
    -0.0003029205147213668f, 0.003808752013890615f, -0.027219029917056003f,
     0.3644418948353314f,    0.4813596512583722f,   -0.1432942383508097f,
     0.03169508781149298f,  -0.0033824159510061256f };
__device__ __constant__ float FHE[8] = {
     0.0033824159510061256f, -0.03169508781149298f,  0.1432942383508097f,
    -0.4813596512583722f,   -0.3644418948353314f,    0.027219029917056003f,
    -0.003808752013890615f,  0.0003029205147213668f };
__device__ __constant__ float FHO[8] = {
    -0.0005421323317911481f, 0.007607487324917605f, -0.061273359067658524f,
     0.7771857517005235f,   -0.05194583810770904f,   0.049137179673607506f,
    -0.01495225833704823f,   0.0018899503327594609f };

__device__ __forceinline__ int reflect(int q, int L) {
    q = (q < 0) ? -q : q;
    return (q >= L) ? (2 * L - 2 - q) : q;
}

__device__ __forceinline__ void load20(const float* __restrict__ lds, int base,
                                       float w[20]) {
#pragma unroll
    for (int k = 0; k < 5; ++k) {
        const float4 v = *reinterpret_cast<const float4*>(&lds[base + 4 * k]);
        w[4 * k] = v.x; w[4 * k + 1] = v.y; w[4 * k + 2] = v.z; w[4 * k + 3] = v.w;
    }
}

__device__ __forceinline__ void conv2(const float w[20], float& lo0, float& hi0,
                                      float& lo1, float& hi1) {
    lo0 = hi0 = lo1 = hi1 = 0.f;
#pragma unroll
    for (int t = 0; t < 16; ++t) {
        const float cl = FL[t], ch = FH[t];
        lo0 = fmaf(w[t], cl, lo0);
        hi0 = fmaf(w[t], ch, hi0);
        lo1 = fmaf(w[t + 2], cl, lo1);
        hi1 = fmaf(w[t + 2], ch, hi1);
    }
}

// ======================= F03: levels 0-3 in one kernel =======================
// One stage: parent virtual tile IN (Pin subrows, stride Sin, window start
// pin_lo = 2*o_lo-14), child virtual tile OUT (2*Pin subrows, stride Sout,
// window [o_lo, o_lo+Wout), child length Lc). Blind fast path; edge groups
// recompute at reflect(q,Lc) with rel window base 2*(jr - o_lo).
template <int Pin, int Wout, int Sin, int Sout, int Lc>
__device__ __forceinline__ void f03_stage(const float* __restrict__ in,
                                          float* __restrict__ out, int o_lo) {
    constexpr int GPS = Wout / 2;
    for (int g = threadIdx.x; g < Pin * GPS; g += BT) {
        const int r = g / GPS;                  // compile-time divisor
        const int u = g - r * GPS;
        const int s0 = 2 * u;
        const int q0 = o_lo + s0;
        const float* pin = in + r * Sin;
        float lo0, hi0, lo1, hi1;
        if (q0 >= 0 && q0 + 2 <= Lc) {          // q0, q0+1 both genuine
            float w[20];
            load20(pin, 4 * u, w);
            conv2(w, lo0, hi0, lo1, hi1);
        } else {                                // segs 0/15 only
#pragma unroll
            for (int e = 0; e < 2; ++e) {
                const int jr = reflect(q0 + e, Lc);
                const int rb = 2 * (jr - o_lo);
                float l = 0.f, h = 0.f;
#pragma unroll
                for (int t = 0; t < 16; ++t) {
                    const float v = pin[rb + t];
                    l = fmaf(v, FL[t], l);
                    h = fmaf(v, FH[t], h);
                }
                if (e == 0) { lo0 = l; hi0 = h; } else { lo1 = l; hi1 = h; }
            }
        }
        *reinterpret_cast<float2*>(&out[(2 * r) * Sout + s0])     = make_float2(lo0, lo1);
        *reinterpret_cast<float2*>(&out[(2 * r + 1) * Sout + s0]) = make_float2(hi0, hi1);
    }
}

__global__ __launch_bounds__(BT, 8) void dwt_f03(
    const float* __restrict__ x, float* __restrict__ y) {
    constexpr int M  = 258;                     // lev3 positions per segment
    constexpr int WX = 4338, SX = 4340;         // x tile
    constexpr int W0 = 2162, S0 = 2164;         // lev0 tile (2 subrows)
    constexpr int W1 = 1074, S1 = 1076;         // lev1 tile (4 subrows)
    constexpr int W2 = 530,  S2 = 532;          // lev2 tile (8 subrows)
    __shared__ __align__(16) float bufA[4340];  // xs | lev1 (4*1076=4304)
    __shared__ __align__(16) float bufB[4328];  // lev0 (2*2164) | lev2 (8*532)

    const int seg = blockIdx.x;
    const int n   = blockIdx.y;
    const int b0  = M * seg;
    const int a2  = 2 * b0 - 14;
    const int c1  = 4 * b0 - 42;
    const int a0  = 8 * b0 - 98;
    const int px0 = 16 * b0 - 210;
    const float* row = x + (size_t)n * 65536;

    // ---- x-tile fill (virtual: reflect folded into fill) ----
    if (px0 >= 0 && px0 + WX <= 65536) {
        const float2* rp = reinterpret_cast<const float2*>(row + px0);
        for (int h = threadIdx.x; h < WX / 2; h += BT)
            *reinterpret_cast<float2*>(&bufA[2 * h]) = rp[h];
    } else {
        for (int p = threadIdx.x; p < WX; p += BT)
            bufA[p] = row[reflect(px0 + p, 65536)];
    }
    __syncthreads();

    f03_stage<1, W0, SX, S0, 32775>(bufA, bufB, a0);   // x    -> lev0 (2)
    __syncthreads();
    f03_stage<2, W1, S0, S1, 16395>(bufB, bufA, c1);   // lev0 -> lev1 (4)
    __syncthreads();
    f03_stage<4, W2, S1, S2, 8205>(bufA, bufB, a2);    // lev1 -> lev2 (8)
    __syncthreads();

    // ---- final: lev2 -> lev3 genuine, global (rows 16n+c, stride 4112) ----
    {
        constexpr int GPS = M / 2;              // 129
        float* yg = y + (size_t)(16 * n) * 4112;
        for (int g = threadIdx.x; g < 8 * GPS; g += BT) {
            const int r  = g / GPS;
            const int u  = g - r * GPS;
            const int j0 = b0 + 2 * u;
            if (j0 >= 4110) continue;
            float w[20];
            load20(bufB + r * S2, 4 * u, w);
            float lo0, hi0, lo1, hi1;
            conv2(w, lo0, hi0, lo1, hi1);
            float* y0 = yg + (size_t)(2 * r) * 4112 + j0;
            float* y1 = y0 + 4112;
            if (j0 + 1 < 4110) {
                *reinterpret_cast<float2*>(y0) = make_float2(lo0, lo1);
                *reinterpret_cast<float2*>(y1) = make_float2(hi0, hi1);
            } else {
                y0[0] = lo0; y1[0] = hi0;
            }
        }
    }
}

// ================= R7 polyphase quad kernel (verbatim) =================
__device__ __forceinline__ void eo_put(float* __restrict__ E, float* __restrict__ O,
                                       int q, float v) {
    ((q & 1) ? O : E)[8 + (q >> 1)] = v;
}

__device__ __forceinline__ void read12(const float* __restrict__ b, int w0,
                                       float* __restrict__ r) {
#pragma unroll
    for (int k = 0; k < 3; ++k) {
        const float4 v = *reinterpret_cast<const float4*>(&b[w0 + 4 * k]);
        r[4 * k] = v.x; r[4 * k + 1] = v.y; r[4 * k + 2] = v.z; r[4 * k + 3] = v.w;
    }
}

template <int OFF>
__device__ __forceinline__ void conv4eo(const float e[12], const float o[12],
                                        float lo[4], float hi[4]) {
#pragma unroll
    for (int d = 0; d < 4; ++d) { lo[d] = 0.f; hi[d] = 0.f; }
#pragma unroll
    for (int s = 0; s < 8; ++s) {
        const float fle = FLE[s], flo = FLO[s], fhe = FHE[s], fho = FHO[s];
#pragma unroll
        for (int d = 0; d < 4; ++d) {
            const float ev = e[OFF + d + s], ov = o[OFF + d + s];
            lo[d] = fmaf(ev, fle, lo[d]);
            lo[d] = fmaf(ov, flo, lo[d]);
            hi[d] = fmaf(ev, fhe, hi[d]);
            hi[d] = fmaf(ov, fho, hi[d]);
        }
    }
}

template <int Ls, int P, int Sin, int Sout, bool LOG>
__device__ __forceinline__ void stage_eo(const float* __restrict__ inb,
                                         float* __restrict__ outb,
                                         float* __restrict__ outg) {
    constexpr int H    = Ls / 2;
    constexpr int LOUT = H + 7;
    constexpr int GPS  = (LOUT + 3) / 4;
    constexpr int SEi  = Sin / 2;
    constexpr int SEo  = Sout / 2;
    for (int g = threadIdx.x; g < P * GPS; g += BT) {
        const int p  = g / GPS;
        const int u  = g - p * GPS;
        const int j0 = 4 * u;
        const float* Ei = inb + p * Sin;
        const float* Oi = Ei + SEi;
        float e[12], o[12];
        read12(Ei, 4 * u, e);
        read12(Oi, 4 * u, o);
        float lo[4], hi[4];
        conv4eo<1>(e, o, lo, hi);
        if (LOG) {
            float r0[4], r1[4];
#pragma unroll
            for (int d = 0; d < 4; ++d) {
                r0[d] = __logf(fmaf(lo[d], lo[d], 1e-12f));
                r1[d] = __logf(fmaf(hi[d], hi[d], 1e-12f));
            }
            float* y0 = outg + (2 * p) * 270 + j0;
            float* y1 = y0 + 270;
            if (j0 + 3 < 270) {
                *reinterpret_cast<float2*>(y0)     = make_float2(r0[0], r0[1]);
                *reinterpret_cast<float2*>(y0 + 2) = make_float2(r0[2], r0[3]);
                *reinterpret_cast<float2*>(y1)     = make_float2(r1[0], r1[1]);
                *reinterpret_cast<float2*>(y1 + 2) = make_float2(r1[2], r1[3]);
            } else {
                *reinterpret_cast<float2*>(y0) = make_float2(r0[0], r0[1]);
                *reinterpret_cast<float2*>(y1) = make_float2(r1[0], r1[1]);
            }
        } else {
            float* El = outb + (2 * p) * Sout;
            float* Ol = El + SEo;
            float* Eh = outb + (2 * p + 1) * Sout;
            float* Oh = Eh + SEo;
            if (j0 + 3 < LOUT) {
                *reinterpret_cast<float2*>(&El[8 + 2 * u]) = make_float2(lo[0], lo[2]);
                *reinterpret_cast<float2*>(&Ol[8 + 2 * u]) = make_float2(lo[1], lo[3]);
                *reinterpret_cast<float2*>(&Eh[8 + 2 * u]) = make_float2(hi[0], hi[2]);
                *reinterpret_cast<float2*>(&Oh[8 + 2 * u]) = make_float2(hi[1], hi[3]);
            } else {
#pragma unroll
                for (int d = 0; d < 4; ++d)
                    if (j0 + d < LOUT) {
                        eo_put(El, Ol, j0 + d, lo[d]);
                        eo_put(Eh, Oh, j0 + d, hi[d]);
                    }
            }
            if (j0 <= 14 || j0 >= LOUT - 18) {
#pragma unroll
                for (int d = 0; d < 4; ++d) {
                    const int j = j0 + d;
                    if (j >= 1 && j <= 14) {
                        eo_put(El, Ol, -j, lo[d]);
                        eo_put(Eh, Oh, -j, hi[d]);
                    }
                    if (j >= LOUT - 15 && j <= LOUT - 2) {
                        eo_put(El, Ol, 2 * LOUT - 2 - j, lo[d]);
                        eo_put(Eh, Oh, 2 * LOUT - 2 - j, hi[d]);
                    }
                }
            }
        }
    }
}

__global__ __launch_bounds__(BT, 8) void dwt_quad_eo(
    const float* __restrict__ x, float* __restrict__ y) {
    __shared__ __align__(16) float bufA[4320];  // in 4152 | s2-out 4x1080
    __shared__ __align__(16) float bufB[4544];  // s1-out 2x2104 | s3-out 8x568

    const int m = blockIdx.x;
    const float* row = x + (size_t)m * 4112;
    float* Ex = bufA;
    float* Ox = bufA + 2076;
    for (int i = threadIdx.x; i < 2055; i += BT) {
        const float2 v = reinterpret_cast<const float2*>(row)[i];
        Ex[8 + i] = v.x;
        Ox[8 + i] = v.y;
        if (i >= 1 && i <= 7)       eo_put(Ex, Ox, -2 * i, v.x);
        if (i <= 6)                 eo_put(Ex, Ox, -(2 * i + 1), v.y);
        if (i >= 2048)              eo_put(Ex, Ox, 8218 - 2 * i, v.x);
        if (i >= 2047 && i <= 2053) eo_put(Ex, Ox, 8217 - 2 * i, v.y);
    }
    __syncthreads();
    stage_eo<4110, 1, 4152, 2104, false>(bufA, bufB, nullptr);  // -> 2x2062
    __syncthreads();
    stage_eo<2062, 2, 2104, 1080, false>(bufB, bufA, nullptr);  // -> 4x1038
    __syncthreads();
    stage_eo<1038, 4, 1080, 568, false>(bufA, bufB, nullptr);   // -> 8x526
    __syncthreads();
    stage_eo<526, 8, 568, 0, true>(bufB, nullptr, y + (size_t)m * 4320); // 16x270
}

extern "C" void kernel_launch(void* const* d_in, const int* in_sizes, int n_in,
                              void* d_out, int out_size, void* d_ws, size_t ws_size,
                              hipStream_t stream) {
    const float* in = (const float*)d_in[0];
    float* out = (float*)d_out;
    float* wsB = (float*)d_ws;              // lev3: 2048 rows, stride 4112
    (void)ws_size; (void)out_size; (void)n_in; (void)in_sizes;

    // F03: levels 0-3; 16 segs x 128 rows
    { dim3 g(16, 128); dwt_f03<<<g, BT, 0, stream>>>(in, wsB); }
    // F47: levels 4-7 (+log)
    dwt_quad_eo<<<2048, BT, 0, stream>>>(wsB, out);
}